// Round 20
// baseline (78.439 us; speedup 1.0000x reference)
//
#include <hip/hip_runtime.h>
#include <hip/hip_bf16.h>
#include <stdint.h>

// Problem constants
#define NB    32    // batch
#define CIN   128
#define HH    56
#define WW    56
#define COUT  256

// ws layout: wpack only (bf16, 36*8192 = 294,912 elems)
typedef __attribute__((ext_vector_type(4))) float f32x4;
typedef __attribute__((ext_vector_type(8))) short bf16x8;

__device__ __forceinline__ unsigned short f2bf(float f) {
    union { float f; unsigned u; } v; v.f = f;
    unsigned r = v.u + 0x7FFFu + ((v.u >> 16) & 1u);
    return (unsigned short)(r >> 16);
}

// ---------------------------------------------------------------------------
// build_weight: compose per-output-channel filters.
// wpack layout (R13-verified): [tile(36)][wid(4)][mf(4)][lane(64)][kin(8)]
//   elem = tile*8192 + wid*2048 + mf*512 + lane*8 + kin; tile = pos*4+cib,
//   o = wid*64+mf*16+fl, lane = kpos*16+fl, ci = cib*32+kpos*8+kin.
// ---------------------------------------------------------------------------
__global__ __launch_bounds__(256) void build_weight(
    const float* __restrict__ dict, const float* __restrict__ coef,
    const int* __restrict__ idxw, unsigned short* __restrict__ wpack) {
    int o = blockIdx.x;
    int tid = threadIdx.x;
    bool mode64 = (idxw[1] == 0) && (idxw[3] == 0) && (idxw[5] == 0) &&
                  (idxw[7] == 0) && (idxw[9] == 0) && (idxw[11] == 0) &&
                  (idxw[13] == 0) && (idxw[15] == 0);
    float c[8]; int di[8];
#pragma unroll
    for (int s = 0; s < 8; ++s) {
        c[s]  = coef[o * 8 + s];
        di[s] = mode64 ? idxw[(o * 8 + s) * 2] : idxw[o * 8 + s];
    }
    const int wid = o >> 6, mf = (o >> 4) & 3, fl = o & 15;
    for (int j = tid; j < 9 * 128; j += 256) {
        int pos = j >> 7;          // 0..8
        int ci  = j & 127;
        int kh = pos / 3, kw = pos - kh * 3;
        float v = 0.f;
#pragma unroll
        for (int s = 0; s < 8; ++s)
            v += c[s] * dict[((di[s] * CIN + ci) * 3 + kh) * 3 + kw];
        int tile = pos * 4 + (ci >> 5);
        int kpos = (ci >> 3) & 3, kin = ci & 7;
        wpack[tile * 8192 + wid * 2048 + mf * 512 + (kpos * 16 + fl) * 8 + kin]
            = f2bf(v);
    }
}

// ---------------------------------------------------------------------------
// Per-cib slice pack (R20): wave `wid` packs slab channel c*4+wid (8 ci) of
// slice c, all 3 rows; lane = iw (coalesced loads, verified conflict-free
// 16B writes). Pad lanes/rows write zeros via select on clamped addresses.
// ---------------------------------------------------------------------------
__device__ __forceinline__ void pack_slice(
    const float* __restrict__ xb, int oh, int wid, int lane, int c,
    unsigned short* Bl) {
    const int iw = lane;
    const bool vw = (iw >= 1) && (iw <= WW);
    const int w = vw ? iw - 1 : 0;
    const float* base = xb + ((size_t)(c * 32 + wid * 8) * HH) * WW + w;
    float v[3][8];
#pragma unroll
    for (int row = 0; row < 3; ++row) {
        int h = oh + row - 1;
        int hc = h < 0 ? 0 : (h >= HH ? HH - 1 : h);
#pragma unroll
        for (int j = 0; j < 8; ++j)                 // 24 independent loads
            v[row][j] = base[((size_t)j * HH + hc) * WW];
    }
#pragma unroll
    for (int row = 0; row < 3; ++row) {
        int h = oh + row - 1;
        bool valid = vw && (h >= 0) && (h < HH);
        bf16x8 pv;
#pragma unroll
        for (int j = 0; j < 8; ++j)
            pv[j] = valid ? (short)f2bf(v[row][j]) : (short)0;
        *(bf16x8*)&Bl[((row * 16 + c * 4 + wid) * 512) + iw * 8] = pv;
    }
}

// ---------------------------------------------------------------------------
// Main: FUSED pack + implicit-GEMM conv, R20 = R19 + per-cib slice packing.
// R19 post-mortem: fusion won (78.3us total) but the pack ran fully serial
// before the barrier (~8us). cib c only reads slab ch c*4..c*4+3, so slices
// are disjoint: prologue packs slice 0 only; cib c packs slice c+1 at its
// top (hidden under the ~2000-cyc tap region + 2 other resident blocks),
// with one __syncthreads per cib for cross-wave visibility.
//  - slab stride 512 (verified 0-conflict reads), main loop = R15 verbatim.
//  - (256,3): LDS 49.7 KB -> 3 blocks/CU; regs ~90 arch + 64 AGPR.
// ---------------------------------------------------------------------------
__global__ __launch_bounds__(256, 3) void conv_mfma(
    const float* __restrict__ x,
    const unsigned short* __restrict__ wpack,
    float* __restrict__ out) {
    // slab: elem = (row*16 + ch)*512 + iw*8 + kin ; +128 pad (junk-col reads)
    __shared__ unsigned short Bl[3 * 16 * 512 + 128];

    int tid  = threadIdx.x;
    int lane = tid & 63;
    int wid  = tid >> 6;       // 0..3 = Cout slice of 64 (and pack wave id)

    // XCD-bijective swizzle: 1792 = 8 * 224; each XCD gets 4 consecutive b's
    int flat = blockIdx.x;
    int swz  = (flat & 7) * 224 + (flat >> 3);
    int b    = swz / 56;       // 0..31
    int oh   = swz % 56;       // output row

    const int klane = lane >> 4;   // k-group (0..3)
    const int fl    = lane & 15;

    const float* xb = x + (size_t)b * CIN * HH * WW;

    // A-fragment base (coalesced): af(tile,mf) = ap0 + tile*8192 + mf*512 elems
    const unsigned short* ap0 = wpack + (size_t)wid * 2048 + lane * 8;

    // ---- issue A(tile 0) early: latency hides under the prologue pack ----
    bf16x8 af[2][4];
#pragma unroll
    for (int mf = 0; mf < 4; ++mf)
        af[0][mf] = *(const bf16x8*)(ap0 + mf * 512);

    // ---- prologue: pack slice 0 only (24 loads vs R19's 96) ----
    pack_slice(xb, oh, wid, lane, 0, Bl);

    f32x4 acc[4][4];
    f32x4 zero = {0.f, 0.f, 0.f, 0.f};
#pragma unroll
    for (int i = 0; i < 4; ++i)
#pragma unroll
        for (int j = 0; j < 4; ++j) acc[i][j] = zero;

    __syncthreads();   // slice 0 resident

    const unsigned short* apc = ap0;                       // += 8192/cib
    const unsigned short* bl0 = &Bl[klane * 512 + fl * 8];

#pragma unroll 2
    for (int cib = 0; cib < 4; ++cib) {
        // ---- pack slice cib+1 (disjoint ch; consumed after the barrier) ----
        if (cib < 3)
            pack_slice(xb, oh, wid, lane, cib + 1, Bl);

        const unsigned short* bcur = bl0 + cib * 2048;     // 4 ch per cib

#pragma unroll
        for (int pos = 0; pos < 9; ++pos) {
            const int kh = pos / 3, kw = pos - kh * 3;
            const int cur = (cib + pos) & 1;   // STATIC under unroll-2 cib

            // ---- prefetch A(next step) into the free set (ping-pong) ----
            if (pos < 8) {
#pragma unroll
                for (int mf = 0; mf < 4; ++mf)
                    af[cur ^ 1][mf] =
                        *(const bf16x8*)(apc + (pos + 1) * 32768 + mf * 512);
            } else if (cib < 3) {
#pragma unroll
                for (int mf = 0; mf < 4; ++mf)
                    af[cur ^ 1][mf] = *(const bf16x8*)(apc + 8192 + mf * 512);
            }

            // ---- B fragments from resident slab (imm-offset ds_read) ----
            bf16x8 bfr[4];
#pragma unroll
            for (int nf = 0; nf < 4; ++nf)
                bfr[nf] = *(const bf16x8*)(bcur + kh * 8192 + (nf * 16 + kw) * 8);

            // ---- 16 MFMA on af[cur] (loaded a full step ago) ----
            __builtin_amdgcn_s_setprio(1);
#pragma unroll
            for (int mf = 0; mf < 4; ++mf)
#pragma unroll
                for (int nf = 0; nf < 4; ++nf)
                    acc[mf][nf] = __builtin_amdgcn_mfma_f32_16x16x32_bf16(
                        af[cur][mf], bfr[nf], acc[mf][nf], 0, 0, 0);
            __builtin_amdgcn_s_setprio(0);
        }
        apc += 8192;

        // ---- slice cib+1 visible to all waves ----
        if (cib < 3) __syncthreads();
    }

    // Epilogue: C/D layout col = lane&15, row = (lane>>4)*4 + reg (m89-verified)
#pragma unroll
    for (int nf = 0; nf < 4; ++nf) {
        int ow = nf * 16 + fl;
        if (ow < WW) {
#pragma unroll
            for (int mf = 0; mf < 4; ++mf) {
                int ob = wid * 64 + mf * 16 + (lane >> 4) * 4;
                float* dst = out + (((size_t)b * COUT + ob) * HH + oh) * WW + ow;
#pragma unroll
                for (int r = 0; r < 4; ++r)
                    dst[(size_t)r * HH * WW] = acc[mf][nf][r];
            }
        }
    }
}

extern "C" void kernel_launch(void* const* d_in, const int* in_sizes, int n_in,
                              void* d_out, int out_size, void* d_ws, size_t ws_size,
                              hipStream_t stream) {
    const float* x    = (const float*)d_in[0];
    const float* dict = (const float*)d_in[1];
    const float* coef = (const float*)d_in[2];
    const int*   idxw = (const int*)d_in[3];
    float* out = (float*)d_out;

    unsigned short* wpack = (unsigned short*)d_ws;

    build_weight<<<dim3(COUT), dim3(256), 0, stream>>>(dict, coef, idxw, wpack);
    conv_mfma<<<dim3(NB * 56), dim3(256), 0, stream>>>(x, wpack, out);
}